// Round 2
// baseline (755.906 us; speedup 1.0000x reference)
//
#include <hip/hip_runtime.h>
#include <hip/hip_bf16.h>

typedef unsigned short u16;
typedef unsigned int u32;
typedef __bf16 bf16x8 __attribute__((ext_vector_type(8)));
typedef float f32x4 __attribute__((ext_vector_type(4)));

#define NE 300000
#define NBLK 2344            // ceil(300000 / 128)

// workspace layout (unchanged)
#define WS_WT1   0           // u16: W1^T, 3 chunks of [128 n][128 k]
#define WS_WT2   49152       // u16: W2^T  [128 n][128 k]
#define WS_WGTP  65536       // u16: [48 n][128 k]: 0-15 wg^T, 16-31 wt^T, 32-47 wp^T
#define WS_WO    71680       // u16: Wo^T zero-padded [128 n][32 k] (k>=16 -> 0)
#define WS_TOTAL 75776
#define WS_BF32  37888       // f32 index of bias block: b1[128] b2[128] bg[16] bt[16] bp[16] bo[128]
#define NBIAS    432
#define WS_FLAG32 38320      // u32 index of dtype flag; 1 = bf16 inputs, 0 = f32

__device__ __forceinline__ float bs2f(u16 u) {
    union { u32 i; float f; } v; v.i = ((u32)u) << 16; return v.f;
}
__device__ __forceinline__ u16 f2bs(float f) {
    __hip_bfloat16 h = __float2bfloat16(f);
    u16 u; __builtin_memcpy(&u, &h, 2); return u;
}
__device__ __forceinline__ __bf16 f2b(float f) {
    __hip_bfloat16 h = __float2bfloat16(f);
    __bf16 b; __builtin_memcpy(&b, &h, 2); return b;
}

// XOR-swizzled per-wave LDS tile [32 rows][128 u16]; 16B chunks, chunk' = chunk ^ (row & 15)
#define LDFRAG(base, lr, kch) (*(const bf16x8*)&(base)[(lr) * 128 + ((((kch) ^ ((lr) & 15))) << 3)])
#define SWZ(lr, col) ((lr) * 128 + (((((col) >> 3) ^ ((lr) & 15))) << 3) + ((col) & 7))

// ---- dtype sniffer (unchanged) ----
__global__ void sniff_kernel(const void* __restrict__ src, u32* __restrict__ wsu) {
    if (threadIdx.x != 0) return;
    const u32* p = (const u32*)src;
    int score = 0;
    for (int i = 0; i < 64; ++i) {
        u32 w = p[i];
        int e = (w >> 7) & 0xFF;
        score += (e > 100 && e < 150) ? 1 : 0;
    }
    wsu[WS_FLAG32] = (score >= 40) ? 1u : 0u;
}

__global__ void prep_kernel(const void* __restrict__ w1, const void* __restrict__ w2,
                            const void* __restrict__ wg, const void* __restrict__ wt,
                            const void* __restrict__ wp, const void* __restrict__ wo,
                            const void* __restrict__ b1, const void* __restrict__ b2,
                            const void* __restrict__ bg, const void* __restrict__ bt,
                            const void* __restrict__ bp, const void* __restrict__ bo,
                            u16* __restrict__ ws) {
    const bool isbf = ((const u32*)ws)[WS_FLAG32] != 0;
    auto ldf = [&](const void* p, int idx) -> float {
        return isbf ? bs2f(((const u16*)p)[idx]) : ((const float*)p)[idx];
    };
    int id = blockIdx.x * 256 + threadIdx.x;
    if (id < WS_TOTAL) {
        float v;
        if (id < WS_WT2) {                       // W1^T chunks
            int c = id >> 14, r = id & 16383, n = r >> 7, k = r & 127;
            v = ldf(w1, (c * 128 + k) * 128 + n);
        } else if (id < WS_WGTP) {               // W2^T
            int r = id - WS_WT2, n = r >> 7, k = r & 127;
            v = ldf(w2, k * 128 + n);
        } else if (id < WS_WO) {                 // [wg|wt|wp]^T
            int r = id - WS_WGTP, n = r >> 7, k = r & 127;
            if (n < 16)      v = ldf(wg, k * 16 + n);
            else if (n < 32) v = ldf(wt, k * 16 + (n - 16));
            else             v = ldf(wp, k * 16 + (n - 32));
        } else {                                 // Wo^T zero-padded to K=32
            int r = id - WS_WO, n = r >> 5, k = r & 31;
            v = (k < 16) ? ldf(wo, k * 128 + n) : 0.f;
        }
        ws[id] = f2bs(v);
    } else if (id < WS_TOTAL + NBIAS) {
        int b = id - WS_TOTAL;
        float v;
        if (b < 128)      v = ldf(b1, b);
        else if (b < 256) v = ldf(b2, b - 128);
        else if (b < 272) v = ldf(bg, b - 256);
        else if (b < 288) v = ldf(bt, b - 272);
        else if (b < 304) v = ldf(bp, b - 288);
        else              v = ldf(bo, b - 304);
        ((float*)ws)[WS_BF32 + b] = v;
    }
}

// K=128 MFMA pass: A fragments from wave-private LDS tile, B fragments direct from
// global (L2-resident weights, [n][k] layout, n-stride 128 u16).
#define GEMM_K128_L2(NACC, ACC, BP)                                                   \
    _Pragma("unroll")                                                                 \
    for (int kk = 0; kk < 4; ++kk) {                                                  \
        const int kch = kk * 4 + l4;                                                  \
        bf16x8 af0 = LDFRAG(mls, l15, kch);                                           \
        bf16x8 af1 = LDFRAG(mls, 16 + l15, kch);                                      \
        _Pragma("unroll")                                                             \
        for (int c = 0; c < NACC; ++c) {                                              \
            uint4 bw = *(const uint4*)((BP) + (16 * c + l15) * 128 + kch * 8);        \
            bf16x8 bb; __builtin_memcpy(&bb, &bw, 16);                                \
            ACC[0][c] = __builtin_amdgcn_mfma_f32_16x16x32_bf16(af0, bb, ACC[0][c], 0, 0, 0); \
            ACC[1][c] = __builtin_amdgcn_mfma_f32_16x16x32_bf16(af1, bb, ACC[1][c], 0, 0, 0); \
        }                                                                             \
    }

// Fully wave-private kernel: every phase touches only the wave's own 32 edge rows,
// B operands come from L2, so there are ZERO __syncthreads(). LDS = 4 x 8KB
// wave-private scratch, reused in sequence: h -> h2 -> projF -> (y over projF tail).
// LDS ops within a wave are in-order, and all overlapping writes come after the
// reads of the same region in program order (attention hoists its reads to regs).
__launch_bounds__(256, 4)
__global__ void fused_kernel(const void* __restrict__ gsrc, const void* __restrict__ gtgt,
                             const void* __restrict__ gea,
                             const u16* __restrict__ ws, void* __restrict__ gout) {
    __shared__ __align__(16) u16 ls[16384];        // 32 KB total, 8 KB per wave

    const int t   = threadIdx.x;
    const int w   = t >> 6;
    const int l   = t & 63;
    const int l15 = l & 15;
    const int l4  = l >> 4;
    u16* mls = ls + (w << 12);                     // wave-private 4096 u16
    const long e0 = (long)blockIdx.x * 128 + 32 * w;   // wave's first edge
    const bool isbf = ((const u32*)ws)[WS_FLAG32] != 0;
    const float* wsF = (const float*)ws + WS_BF32;

    long geA = e0 + l15;      if (geA >= NE) geA = NE - 1;
    long geB = e0 + 16 + l15; if (geB >= NE) geB = NE - 1;

    f32x4 acc[2][8];
    #pragma unroll
    for (int r = 0; r < 2; ++r)
        #pragma unroll
        for (int c = 0; c < 8; ++c)
            acc[r][c] = (f32x4){0.f, 0.f, 0.f, 0.f};

    // ---- GEMM1: h = relu([src|tgt|ea] @ W1 + b1); A direct from HBM, B from L2 ----
    #pragma unroll
    for (int kc = 0; kc < 3; ++kc) {
        const void* __restrict__ ga = (kc == 0) ? gsrc : (kc == 1) ? gtgt : gea;
        const u16* bp = ws + WS_WT1 + kc * 16384;
        #pragma unroll
        for (int kk = 0; kk < 4; ++kk) {
            const int kch = kk * 4 + l4;
            bf16x8 af0, af1;
            if (isbf) {
                uint4 v0 = *(const uint4*)((const u16*)ga + geA * 128 + kch * 8);
                uint4 v1 = *(const uint4*)((const u16*)ga + geB * 128 + kch * 8);
                __builtin_memcpy(&af0, &v0, 16);
                __builtin_memcpy(&af1, &v1, 16);
            } else {
                const float* f0 = (const float*)ga + geA * 128 + kch * 8;
                const float* f1 = (const float*)ga + geB * 128 + kch * 8;
                f32x4 a0 = *(const f32x4*)f0, a1 = *(const f32x4*)(f0 + 4);
                f32x4 c0 = *(const f32x4*)f1, c1 = *(const f32x4*)(f1 + 4);
                #pragma unroll
                for (int q = 0; q < 4; ++q) {
                    af0[q] = f2b(a0[q]); af0[4 + q] = f2b(a1[q]);
                    af1[q] = f2b(c0[q]); af1[4 + q] = f2b(c1[q]);
                }
            }
            #pragma unroll
            for (int c = 0; c < 8; ++c) {
                uint4 bw = *(const uint4*)(bp + (16 * c + l15) * 128 + kch * 8);
                bf16x8 bb; __builtin_memcpy(&bb, &bw, 16);
                acc[0][c] = __builtin_amdgcn_mfma_f32_16x16x32_bf16(af0, bb, acc[0][c], 0, 0, 0);
                acc[1][c] = __builtin_amdgcn_mfma_f32_16x16x32_bf16(af1, bb, acc[1][c], 0, 0, 0);
            }
        }
    }

    // ---- epilogue1: +b1, relu, h -> wave-private LDS (bf16, swizzled) ----
    float bv[8];
    #pragma unroll
    for (int c = 0; c < 8; ++c) bv[c] = wsF[16 * c + l15];
    #pragma unroll
    for (int r = 0; r < 2; ++r)
        #pragma unroll
        for (int c = 0; c < 8; ++c)
            #pragma unroll
            for (int q = 0; q < 4; ++q) {
                float h = acc[r][c][q] + bv[c];
                h = h > 0.f ? h : 0.f;
                int lr = 16 * r + 4 * l4 + q;
                int col = 16 * c + l15;
                mls[SWZ(lr, col)] = f2bs(h);
            }

    // ---- GEMM2: h2 = h @ W2 + b2 (fp32 acc retained as residual) ----
    #pragma unroll
    for (int r = 0; r < 2; ++r)
        #pragma unroll
        for (int c = 0; c < 8; ++c)
            acc[r][c] = (f32x4){0.f, 0.f, 0.f, 0.f};
    GEMM_K128_L2(8, acc, ws + WS_WT2)

    // epilogue2: +b2; h2 bf16 overwrites h in place (all GEMM2 reads precede in order)
    #pragma unroll
    for (int c = 0; c < 8; ++c) bv[c] = wsF[128 + 16 * c + l15];
    #pragma unroll
    for (int r = 0; r < 2; ++r)
        #pragma unroll
        for (int c = 0; c < 8; ++c)
            #pragma unroll
            for (int q = 0; q < 4; ++q) {
                acc[r][c][q] += bv[c];
                int lr = 16 * r + 4 * l4 + q;
                int col = 16 * c + l15;
                mls[SWZ(lr, col)] = f2bs(acc[r][c][q]);
            }

    // ---- proj: [g|th|ph] = h2 @ [wg|wt|wp] + bias, N = 48 ----
    f32x4 accp[2][3];
    #pragma unroll
    for (int r = 0; r < 2; ++r)
        #pragma unroll
        for (int c = 0; c < 3; ++c)
            accp[r][c] = (f32x4){0.f, 0.f, 0.f, 0.f};
    GEMM_K128_L2(3, accp, ws + WS_WGTP)

    // projF [32][49] f32 overwrites h2 region (all proj reads precede in order)
    float* projF = (float*)mls;
    {
        float pb[3] = {wsF[256 + l15], wsF[272 + l15], wsF[288 + l15]};
        #pragma unroll
        for (int r = 0; r < 2; ++r)
            #pragma unroll
            for (int c = 0; c < 3; ++c)
                #pragma unroll
                for (int q = 0; q < 4; ++q) {
                    int lr = 16 * r + 4 * l4 + q;
                    projF[lr * 49 + 16 * c + l15] = accp[r][c][q] + pb[c];
                }
    }

    // ---- attention: 2 lanes per edge; all projF reads hoisted to regs BEFORE y writes
    // (y region at byte 6144 overlaps projF tail row) ----
    {
        int er = l >> 1, hf = l & 1;
        const float* pr = projF + er * 49;
        float gg[16], tt[16], ss[8];
        #pragma unroll
        for (int j = 0; j < 16; ++j) { gg[j] = pr[j]; tt[j] = pr[16 + j]; }
        #pragma unroll
        for (int ii = 0; ii < 8; ++ii) ss[ii] = pr[32 + hf * 8 + ii];
        float tmax = tt[0], tmin = tt[0];
        #pragma unroll
        for (int j = 1; j < 16; ++j) { tmax = fmaxf(tmax, tt[j]); tmin = fminf(tmin, tt[j]); }
        bf16x8 yv;
        #pragma unroll
        for (int ii = 0; ii < 8; ++ii) {
            float s = ss[ii];
            float m = (s >= 0.f) ? s * tmax : s * tmin;
            float den = 0.f, num = 0.f;
            #pragma unroll
            for (int j = 0; j < 16; ++j) {
                float e = __expf(fmaf(s, tt[j], -m));
                den += e;
                num = fmaf(e, gg[j], num);
            }
            yv[ii] = f2b(num / den);
        }
        u16* yb = mls + 3072;    // [32 rows][32 u16], k>=16 zero-padded, chunk-swizzled
        *(bf16x8*)&yb[er * 32 + ((hf ^ (er & 3)) << 3)] = yv;
        bf16x8 zv; __builtin_memset(&zv, 0, 16);
        *(bf16x8*)&yb[er * 32 + (((2 + hf) ^ (er & 3)) << 3)] = zv;
    }

    // ---- final: acc += y @ Wo  (K=32 zero-padded; Wo direct from L2) ----
    {
        const u16* yb = mls + 3072;
        int m0 = l15, m1 = 16 + l15;
        bf16x8 af0 = *(const bf16x8*)&yb[m0 * 32 + ((l4 ^ (m0 & 3)) << 3)];
        bf16x8 af1 = *(const bf16x8*)&yb[m1 * 32 + ((l4 ^ (m1 & 3)) << 3)];
        #pragma unroll
        for (int c = 0; c < 8; ++c) {
            int n = 16 * c + l15;
            uint4 bw = *(const uint4*)(ws + WS_WO + n * 32 + l4 * 8);
            bf16x8 bq; __builtin_memcpy(&bq, &bw, 16);
            acc[0][c] = __builtin_amdgcn_mfma_f32_16x16x32_bf16(af0, bq, acc[0][c], 0, 0, 0);
            acc[1][c] = __builtin_amdgcn_mfma_f32_16x16x32_bf16(af1, bq, acc[1][c], 0, 0, 0);
        }
    }

    // ---- output epilogue: +bo, wave-private LDS bounce for coalesced stores ----
    #pragma unroll
    for (int c = 0; c < 8; ++c) bv[c] = wsF[304 + 16 * c + l15];

    if (!isbf) {
        // f32 output: two 16-row halves through the 8KB wave scratch
        float* lsF = (float*)mls;
        float* gf = (float*)gout;
        #pragma unroll
        for (int r = 0; r < 2; ++r) {
            #pragma unroll
            for (int c = 0; c < 8; ++c)
                #pragma unroll
                for (int q = 0; q < 4; ++q)
                    lsF[(4 * l4 + q) * 128 + 16 * c + l15] = acc[r][c][q] + bv[c];
            #pragma unroll
            for (int i = 0; i < 8; ++i) {
                int idx = i * 256 + l * 4;           // f32 index in [16][128]
                int lr = idx >> 7, col = idx & 127;
                long ge = e0 + 16 * r + lr;
                if (ge < NE) *(uint4*)(gf + ge * 128 + col) = *(const uint4*)&lsF[idx];
            }
        }
    } else {
        #pragma unroll
        for (int r = 0; r < 2; ++r)
            #pragma unroll
            for (int c = 0; c < 8; ++c)
                #pragma unroll
                for (int q = 0; q < 4; ++q) {
                    int lr = 16 * r + 4 * l4 + q;
                    int col = 16 * c + l15;
                    mls[SWZ(lr, col)] = f2bs(acc[r][c][q] + bv[c]);
                }
        u16* gu = (u16*)gout;
        #pragma unroll
        for (int i = 0; i < 8; ++i) {
            int idx = i * 512 + l * 8;               // u16 index in [32][128]
            int lr = idx >> 7, col = idx & 127;
            long ge = e0 + lr;
            if (ge < NE) {
                uint4 v = *(const uint4*)&mls[SWZ(lr, col)];
                *(uint4*)(gu + ge * 128 + col) = v;
            }
        }
    }
}

extern "C" void kernel_launch(void* const* d_in, const int* in_sizes, int n_in,
                              void* d_out, int out_size, void* d_ws, size_t ws_size,
                              hipStream_t stream) {
    u16* ws = (u16*)d_ws;   // needs 153284 bytes

    sniff_kernel<<<1, 64, 0, stream>>>(d_in[0], (u32*)d_ws);
    prep_kernel<<<(WS_TOTAL + NBIAS + 255) / 256, 256, 0, stream>>>(
        d_in[3], d_in[5], d_in[7], d_in[9], d_in[11], d_in[13],
        d_in[4], d_in[6], d_in[8], d_in[10], d_in[12], d_in[14], ws);
    fused_kernel<<<NBLK, 256, 0, stream>>>(d_in[0], d_in[1], d_in[2], ws, d_out);
}

// Round 3
// 585.072 us; speedup vs baseline: 1.2920x; 1.2920x over previous
//
#include <hip/hip_runtime.h>
#include <hip/hip_bf16.h>

typedef unsigned short u16;
typedef unsigned int u32;
typedef __bf16 bf16x8 __attribute__((ext_vector_type(8)));
typedef float f32x4 __attribute__((ext_vector_type(4)));

#define NE 300000
#define NBLK 2344            // ceil(300000 / 128)

// workspace layout (unchanged)
#define WS_WT1   0           // u16: W1^T, 3 chunks of [128 n][128 k]
#define WS_WT2   49152       // u16: W2^T  [128 n][128 k]
#define WS_WGTP  65536       // u16: [48 n][128 k]: 0-15 wg^T, 16-31 wt^T, 32-47 wp^T
#define WS_WO    71680       // u16: Wo^T zero-padded [128 n][32 k] (k>=16 -> 0)
#define WS_TOTAL 75776
#define WS_BF32  37888       // f32 index of bias block: b1[128] b2[128] bg[16] bt[16] bp[16] bo[128]
#define NBIAS    432
#define WS_FLAG32 38320      // u32 index of dtype flag; 1 = bf16 inputs, 0 = f32

__device__ __forceinline__ float bs2f(u16 u) {
    union { u32 i; float f; } v; v.i = ((u32)u) << 16; return v.f;
}
__device__ __forceinline__ u16 f2bs(float f) {
    __hip_bfloat16 h = __float2bfloat16(f);
    u16 u; __builtin_memcpy(&u, &h, 2); return u;
}
__device__ __forceinline__ __bf16 f2b(float f) {
    __hip_bfloat16 h = __float2bfloat16(f);
    __bf16 b; __builtin_memcpy(&b, &h, 2); return b;
}

// XOR-swizzled per-wave LDS tile [32 rows][128 u16]; 16B chunks, chunk' = chunk ^ (row & 15)
#define LDFRAG(base, lr, kch) (*(const bf16x8*)&(base)[(lr) * 128 + ((((kch) ^ ((lr) & 15))) << 3)])
#define SWZ(lr, col) ((lr) * 128 + (((((col) >> 3) ^ ((lr) & 15))) << 3) + ((col) & 7))

// ---- dtype sniffer (unchanged) ----
__global__ void sniff_kernel(const void* __restrict__ src, u32* __restrict__ wsu) {
    if (threadIdx.x != 0) return;
    const u32* p = (const u32*)src;
    int score = 0;
    for (int i = 0; i < 64; ++i) {
        u32 w = p[i];
        int e = (w >> 7) & 0xFF;
        score += (e > 100 && e < 150) ? 1 : 0;
    }
    wsu[WS_FLAG32] = (score >= 40) ? 1u : 0u;
}

__global__ void prep_kernel(const void* __restrict__ w1, const void* __restrict__ w2,
                            const void* __restrict__ wg, const void* __restrict__ wt,
                            const void* __restrict__ wp, const void* __restrict__ wo,
                            const void* __restrict__ b1, const void* __restrict__ b2,
                            const void* __restrict__ bg, const void* __restrict__ bt,
                            const void* __restrict__ bp, const void* __restrict__ bo,
                            u16* __restrict__ ws) {
    const bool isbf = ((const u32*)ws)[WS_FLAG32] != 0;
    auto ldf = [&](const void* p, int idx) -> float {
        return isbf ? bs2f(((const u16*)p)[idx]) : ((const float*)p)[idx];
    };
    int id = blockIdx.x * 256 + threadIdx.x;
    if (id < WS_TOTAL) {
        float v;
        if (id < WS_WT2) {                       // W1^T chunks
            int c = id >> 14, r = id & 16383, n = r >> 7, k = r & 127;
            v = ldf(w1, (c * 128 + k) * 128 + n);
        } else if (id < WS_WGTP) {               // W2^T
            int r = id - WS_WT2, n = r >> 7, k = r & 127;
            v = ldf(w2, k * 128 + n);
        } else if (id < WS_WO) {                 // [wg|wt|wp]^T
            int r = id - WS_WGTP, n = r >> 7, k = r & 127;
            if (n < 16)      v = ldf(wg, k * 16 + n);
            else if (n < 32) v = ldf(wt, k * 16 + (n - 16));
            else             v = ldf(wp, k * 16 + (n - 32));
        } else {                                 // Wo^T zero-padded to K=32
            int r = id - WS_WO, n = r >> 5, k = r & 31;
            v = (k < 16) ? ldf(wo, k * 128 + n) : 0.f;
        }
        ws[id] = f2bs(v);
    } else if (id < WS_TOTAL + NBIAS) {
        int b = id - WS_TOTAL;
        float v;
        if (b < 128)      v = ldf(b1, b);
        else if (b < 256) v = ldf(b2, b - 128);
        else if (b < 272) v = ldf(bg, b - 256);
        else if (b < 288) v = ldf(bt, b - 272);
        else if (b < 304) v = ldf(bp, b - 288);
        else              v = ldf(bo, b - 304);
        ((float*)ws)[WS_BF32 + b] = v;
    }
}

// K=128 MFMA pass: A fragments from wave-private LDS tile, B fragments direct from
// global (L2-resident weights, [n][k] layout, n-stride 128 u16).
#define GEMM_K128_L2(NACC, ACC, BP)                                                   \
    _Pragma("unroll")                                                                 \
    for (int kk = 0; kk < 4; ++kk) {                                                  \
        const int kch = kk * 4 + l4;                                                  \
        bf16x8 af0 = LDFRAG(mls, l15, kch);                                           \
        bf16x8 af1 = LDFRAG(mls, 16 + l15, kch);                                      \
        _Pragma("unroll")                                                             \
        for (int c = 0; c < NACC; ++c) {                                              \
            uint4 bw = *(const uint4*)((BP) + (16 * c + l15) * 128 + kch * 8);        \
            bf16x8 bb; __builtin_memcpy(&bb, &bw, 16);                                \
            ACC[0][c] = __builtin_amdgcn_mfma_f32_16x16x32_bf16(af0, bb, ACC[0][c], 0, 0, 0); \
            ACC[1][c] = __builtin_amdgcn_mfma_f32_16x16x32_bf16(af1, bb, ACC[1][c], 0, 0, 0); \
        }                                                                             \
    }

// Fully wave-private kernel: every phase touches only the wave's own 32 edge rows,
// B operands come from L2, so there are ZERO __syncthreads(). LDS = 4 x 8KB
// wave-private scratch, reused in sequence: h -> h2 -> projF -> (y over projF tail).
// __launch_bounds__(256, 2): round-2 showed that a floor of 4 waves/EU drives the
// allocator to a 64-VGPR target -> massive scratch spills (WRITE_SIZE 537 MB).
// With min=2 the allocator lands at ~128 VGPRs (proven on the round-0 kernel),
// and the HW can still co-schedule 4 blocks/CU (LDS allows 5).
__launch_bounds__(256, 2)
__global__ void fused_kernel(const void* __restrict__ gsrc, const void* __restrict__ gtgt,
                             const void* __restrict__ gea,
                             const u16* __restrict__ ws, void* __restrict__ gout) {
    __shared__ __align__(16) u16 ls[16384];        // 32 KB total, 8 KB per wave

    const int t   = threadIdx.x;
    const int w   = t >> 6;
    const int l   = t & 63;
    const int l15 = l & 15;
    const int l4  = l >> 4;
    u16* mls = ls + (w << 12);                     // wave-private 4096 u16
    const long e0 = (long)blockIdx.x * 128 + 32 * w;   // wave's first edge
    const bool isbf = ((const u32*)ws)[WS_FLAG32] != 0;
    const float* wsF = (const float*)ws + WS_BF32;

    long geA = e0 + l15;      if (geA >= NE) geA = NE - 1;
    long geB = e0 + 16 + l15; if (geB >= NE) geB = NE - 1;

    f32x4 acc[2][8];
    #pragma unroll
    for (int r = 0; r < 2; ++r)
        #pragma unroll
        for (int c = 0; c < 8; ++c)
            acc[r][c] = (f32x4){0.f, 0.f, 0.f, 0.f};

    // ---- GEMM1: h = relu([src|tgt|ea] @ W1 + b1); A direct from HBM, B from L2 ----
    #pragma unroll
    for (int kc = 0; kc < 3; ++kc) {
        const void* __restrict__ ga = (kc == 0) ? gsrc : (kc == 1) ? gtgt : gea;
        const u16* bp = ws + WS_WT1 + kc * 16384;
        #pragma unroll
        for (int kk = 0; kk < 4; ++kk) {
            const int kch = kk * 4 + l4;
            bf16x8 af0, af1;
            if (isbf) {
                uint4 v0 = *(const uint4*)((const u16*)ga + geA * 128 + kch * 8);
                uint4 v1 = *(const uint4*)((const u16*)ga + geB * 128 + kch * 8);
                __builtin_memcpy(&af0, &v0, 16);
                __builtin_memcpy(&af1, &v1, 16);
            } else {
                const float* f0 = (const float*)ga + geA * 128 + kch * 8;
                const float* f1 = (const float*)ga + geB * 128 + kch * 8;
                f32x4 a0 = *(const f32x4*)f0, a1 = *(const f32x4*)(f0 + 4);
                f32x4 c0 = *(const f32x4*)f1, c1 = *(const f32x4*)(f1 + 4);
                #pragma unroll
                for (int q = 0; q < 4; ++q) {
                    af0[q] = f2b(a0[q]); af0[4 + q] = f2b(a1[q]);
                    af1[q] = f2b(c0[q]); af1[4 + q] = f2b(c1[q]);
                }
            }
            #pragma unroll
            for (int c = 0; c < 8; ++c) {
                uint4 bw = *(const uint4*)(bp + (16 * c + l15) * 128 + kch * 8);
                bf16x8 bb; __builtin_memcpy(&bb, &bw, 16);
                acc[0][c] = __builtin_amdgcn_mfma_f32_16x16x32_bf16(af0, bb, acc[0][c], 0, 0, 0);
                acc[1][c] = __builtin_amdgcn_mfma_f32_16x16x32_bf16(af1, bb, acc[1][c], 0, 0, 0);
            }
        }
    }

    // ---- epilogue1: +b1, relu, h -> wave-private LDS (bf16, swizzled) ----
    float bv[8];
    #pragma unroll
    for (int c = 0; c < 8; ++c) bv[c] = wsF[16 * c + l15];
    #pragma unroll
    for (int r = 0; r < 2; ++r)
        #pragma unroll
        for (int c = 0; c < 8; ++c)
            #pragma unroll
            for (int q = 0; q < 4; ++q) {
                float h = acc[r][c][q] + bv[c];
                h = h > 0.f ? h : 0.f;
                int lr = 16 * r + 4 * l4 + q;
                int col = 16 * c + l15;
                mls[SWZ(lr, col)] = f2bs(h);
            }

    // ---- GEMM2: h2 = h @ W2 + b2 (fp32 acc retained as residual) ----
    #pragma unroll
    for (int r = 0; r < 2; ++r)
        #pragma unroll
        for (int c = 0; c < 8; ++c)
            acc[r][c] = (f32x4){0.f, 0.f, 0.f, 0.f};
    GEMM_K128_L2(8, acc, ws + WS_WT2)

    // epilogue2: +b2; h2 bf16 overwrites h in place (all GEMM2 reads precede in order)
    #pragma unroll
    for (int c = 0; c < 8; ++c) bv[c] = wsF[128 + 16 * c + l15];
    #pragma unroll
    for (int r = 0; r < 2; ++r)
        #pragma unroll
        for (int c = 0; c < 8; ++c)
            #pragma unroll
            for (int q = 0; q < 4; ++q) {
                acc[r][c][q] += bv[c];
                int lr = 16 * r + 4 * l4 + q;
                int col = 16 * c + l15;
                mls[SWZ(lr, col)] = f2bs(acc[r][c][q]);
            }

    // ---- proj: [g|th|ph] = h2 @ [wg|wt|wp] + bias, N = 48 ----
    f32x4 accp[2][3];
    #pragma unroll
    for (int r = 0; r < 2; ++r)
        #pragma unroll
        for (int c = 0; c < 3; ++c)
            accp[r][c] = (f32x4){0.f, 0.f, 0.f, 0.f};
    GEMM_K128_L2(3, accp, ws + WS_WGTP)

    // projF [32][49] f32 overwrites h2 region (all proj reads precede in order)
    float* projF = (float*)mls;
    {
        float pb[3] = {wsF[256 + l15], wsF[272 + l15], wsF[288 + l15]};
        #pragma unroll
        for (int r = 0; r < 2; ++r)
            #pragma unroll
            for (int c = 0; c < 3; ++c)
                #pragma unroll
                for (int q = 0; q < 4; ++q) {
                    int lr = 16 * r + 4 * l4 + q;
                    projF[lr * 49 + 16 * c + l15] = accp[r][c][q] + pb[c];
                }
    }

    // ---- attention: 2 lanes per edge; all projF reads hoisted to regs BEFORE y writes
    // (y region at byte 6144 overlaps projF tail row) ----
    {
        int er = l >> 1, hf = l & 1;
        const float* pr = projF + er * 49;
        float gg[16], tt[16], ss[8];
        #pragma unroll
        for (int j = 0; j < 16; ++j) { gg[j] = pr[j]; tt[j] = pr[16 + j]; }
        #pragma unroll
        for (int ii = 0; ii < 8; ++ii) ss[ii] = pr[32 + hf * 8 + ii];
        float tmax = tt[0], tmin = tt[0];
        #pragma unroll
        for (int j = 1; j < 16; ++j) { tmax = fmaxf(tmax, tt[j]); tmin = fminf(tmin, tt[j]); }
        bf16x8 yv;
        #pragma unroll
        for (int ii = 0; ii < 8; ++ii) {
            float s = ss[ii];
            float m = (s >= 0.f) ? s * tmax : s * tmin;
            float den = 0.f, num = 0.f;
            #pragma unroll
            for (int j = 0; j < 16; ++j) {
                float e = __expf(fmaf(s, tt[j], -m));
                den += e;
                num = fmaf(e, gg[j], num);
            }
            yv[ii] = f2b(num / den);
        }
        u16* yb = mls + 3072;    // [32 rows][32 u16], k>=16 zero-padded, chunk-swizzled
        *(bf16x8*)&yb[er * 32 + ((hf ^ (er & 3)) << 3)] = yv;
        bf16x8 zv; __builtin_memset(&zv, 0, 16);
        *(bf16x8*)&yb[er * 32 + (((2 + hf) ^ (er & 3)) << 3)] = zv;
    }

    // ---- final: acc += y @ Wo  (K=32 zero-padded; Wo direct from L2) ----
    {
        const u16* yb = mls + 3072;
        int m0 = l15, m1 = 16 + l15;
        bf16x8 af0 = *(const bf16x8*)&yb[m0 * 32 + ((l4 ^ (m0 & 3)) << 3)];
        bf16x8 af1 = *(const bf16x8*)&yb[m1 * 32 + ((l4 ^ (m1 & 3)) << 3)];
        #pragma unroll
        for (int c = 0; c < 8; ++c) {
            int n = 16 * c + l15;
            uint4 bw = *(const uint4*)(ws + WS_WO + n * 32 + l4 * 8);
            bf16x8 bq; __builtin_memcpy(&bq, &bw, 16);
            acc[0][c] = __builtin_amdgcn_mfma_f32_16x16x32_bf16(af0, bq, acc[0][c], 0, 0, 0);
            acc[1][c] = __builtin_amdgcn_mfma_f32_16x16x32_bf16(af1, bq, acc[1][c], 0, 0, 0);
        }
    }

    // ---- output epilogue: +bo, wave-private LDS bounce for coalesced stores ----
    #pragma unroll
    for (int c = 0; c < 8; ++c) bv[c] = wsF[304 + 16 * c + l15];

    if (!isbf) {
        // f32 output: two 16-row halves through the 8KB wave scratch
        float* lsF = (float*)mls;
        float* gf = (float*)gout;
        #pragma unroll
        for (int r = 0; r < 2; ++r) {
            #pragma unroll
            for (int c = 0; c < 8; ++c)
                #pragma unroll
                for (int q = 0; q < 4; ++q)
                    lsF[(4 * l4 + q) * 128 + 16 * c + l15] = acc[r][c][q] + bv[c];
            #pragma unroll
            for (int i = 0; i < 8; ++i) {
                int idx = i * 256 + l * 4;           // f32 index in [16][128]
                int lr = idx >> 7, col = idx & 127;
                long ge = e0 + 16 * r + lr;
                if (ge < NE) *(uint4*)(gf + ge * 128 + col) = *(const uint4*)&lsF[idx];
            }
        }
    } else {
        #pragma unroll
        for (int r = 0; r < 2; ++r)
            #pragma unroll
            for (int c = 0; c < 8; ++c)
                #pragma unroll
                for (int q = 0; q < 4; ++q) {
                    int lr = 16 * r + 4 * l4 + q;
                    int col = 16 * c + l15;
                    mls[SWZ(lr, col)] = f2bs(acc[r][c][q] + bv[c]);
                }
        u16* gu = (u16*)gout;
        #pragma unroll
        for (int i = 0; i < 8; ++i) {
            int idx = i * 512 + l * 8;               // u16 index in [32][128]
            int lr = idx >> 7, col = idx & 127;
            long ge = e0 + lr;
            if (ge < NE) {
                uint4 v = *(const uint4*)&mls[SWZ(lr, col)];
                *(uint4*)(gu + ge * 128 + col) = v;
            }
        }
    }
}

extern "C" void kernel_launch(void* const* d_in, const int* in_sizes, int n_in,
                              void* d_out, int out_size, void* d_ws, size_t ws_size,
                              hipStream_t stream) {
    u16* ws = (u16*)d_ws;   // needs 153284 bytes

    sniff_kernel<<<1, 64, 0, stream>>>(d_in[0], (u32*)d_ws);
    prep_kernel<<<(WS_TOTAL + NBIAS + 255) / 256, 256, 0, stream>>>(
        d_in[3], d_in[5], d_in[7], d_in[9], d_in[11], d_in[13],
        d_in[4], d_in[6], d_in[8], d_in[10], d_in[12], d_in[14], ws);
    fused_kernel<<<NBLK, 256, 0, stream>>>(d_in[0], d_in[1], d_in[2], ws, d_out);
}